// Round 1
// baseline (438.861 us; speedup 1.0000x reference)
//
#include <hip/hip_runtime.h>

// SpanPooler: x [1, 64, 2048, 768] fp32, spans [64, 2] int32 -> out [64, 768] fp32
// out[b, :] = mean(x[0, b, a:e, :]) where (a, e) = spans[b], count >= 1.

#define B_SZ 64
#define S_SZ 2048
#define D_SZ 768
#define D4   (D_SZ / 4)   // 192 float4 per row
#define RG   4            // row-groups per block

__global__ __launch_bounds__(D_SZ) void span_mean_kernel(
    const float* __restrict__ x,
    const int* __restrict__ spans,
    float* __restrict__ out) {
    const int b = blockIdx.x;
    const int t = threadIdx.x;          // 0 .. 767
    const int col4 = t % D4;            // which float4 column chunk
    const int rg   = t / D4;            // row-group 0..3

    const int a = spans[2 * b + 0];
    const int e = spans[2 * b + 1];
    int cnt = e - a;
    if (cnt < 1) cnt = 1;

    const float4* row_base = (const float4*)(x + (size_t)b * S_SZ * D_SZ);

    float4 acc = make_float4(0.f, 0.f, 0.f, 0.f);
    for (int r = a + rg; r < e; r += RG) {
        float4 v = row_base[(size_t)r * D4 + col4];
        acc.x += v.x; acc.y += v.y; acc.z += v.z; acc.w += v.w;
    }

    // Reduce the 4 row-groups through LDS.
    __shared__ float4 sm[RG][D4];       // 12 KiB
    sm[rg][col4] = acc;
    __syncthreads();

    if (rg == 0) {
        float4 s0 = sm[0][col4];
        float4 s1 = sm[1][col4];
        float4 s2 = sm[2][col4];
        float4 s3 = sm[3][col4];
        float inv = 1.0f / (float)cnt;
        float4 r;
        r.x = (s0.x + s1.x + s2.x + s3.x) * inv;
        r.y = (s0.y + s1.y + s2.y + s3.y) * inv;
        r.z = (s0.z + s1.z + s2.z + s3.z) * inv;
        r.w = (s0.w + s1.w + s2.w + s3.w) * inv;
        ((float4*)out)[(size_t)b * D4 + col4] = r;
    }
}

extern "C" void kernel_launch(void* const* d_in, const int* in_sizes, int n_in,
                              void* d_out, int out_size, void* d_ws, size_t ws_size,
                              hipStream_t stream) {
    const float* x   = (const float*)d_in[0];
    const int* spans = (const int*)d_in[1];
    float* out       = (float*)d_out;
    span_mean_kernel<<<dim3(B_SZ), dim3(D_SZ), 0, stream>>>(x, spans, out);
}

// Round 2
// 432.570 us; speedup vs baseline: 1.0145x; 1.0145x over previous
//
#include <hip/hip_runtime.h>

// SpanPooler: x [1, 64, 2048, 768] fp32, spans [64, 2] int32 -> out [64, 768] fp32
// out[b, :] = mean(x[0, b, a:e, :]) where (a, e) = spans[b], count >= 1.
//
// Split-K version: grid = (B, SPLITS). Each block accumulates a pre-scaled
// partial (sum * 1/cnt) over its row slice and atomicAdds into d_out, which
// is zeroed first with hipMemsetAsync (d_out is poisoned 0xAA by the harness).

#define B_SZ   64
#define S_SZ   2048
#define D_SZ   768
#define D4     (D_SZ / 4)   // 192 float4 per row
#define RG     4            // row-groups per block (768 threads / 192 cols)
#define SPLITS 8            // blocks per batch -> 512 blocks total

__global__ __launch_bounds__(D_SZ) void span_mean_partial(
    const float* __restrict__ x,
    const int* __restrict__ spans,
    float* __restrict__ out) {
    const int b  = blockIdx.x;
    const int s  = blockIdx.y;          // split index 0..SPLITS-1
    const int t  = threadIdx.x;         // 0 .. 767
    const int col4 = t % D4;            // float4 column chunk
    const int rg   = t / D4;            // row-group 0..3

    const int a = spans[2 * b + 0];
    const int e = spans[2 * b + 1];
    int cnt = e - a;
    if (cnt < 1) cnt = 1;
    const float inv = 1.0f / (float)cnt;

    const float4* row_base = (const float4*)(x + (size_t)b * S_SZ * D_SZ);

    // Rows covered by this (split, row-group): a + s + SPLITS*rg + SPLITS*RG*k.
    // Offsets s + SPLITS*rg enumerate [0, 32) exactly once -> each row once.
    float4 acc = make_float4(0.f, 0.f, 0.f, 0.f);
    for (int r = a + s + SPLITS * rg; r < e; r += SPLITS * RG) {
        float4 v = row_base[(size_t)r * D4 + col4];
        acc.x += v.x; acc.y += v.y; acc.z += v.z; acc.w += v.w;
    }

    // Reduce the 4 row-groups through LDS, then one atomicAdd set per column.
    __shared__ float4 sm[RG][D4];       // 12 KiB
    sm[rg][col4] = acc;
    __syncthreads();

    if (rg == 0) {
        float4 s0 = sm[0][col4];
        float4 s1 = sm[1][col4];
        float4 s2 = sm[2][col4];
        float4 s3 = sm[3][col4];
        float* o = out + (size_t)b * D_SZ + col4 * 4;
        atomicAdd(o + 0, (s0.x + s1.x + s2.x + s3.x) * inv);
        atomicAdd(o + 1, (s0.y + s1.y + s2.y + s3.y) * inv);
        atomicAdd(o + 2, (s0.z + s1.z + s2.z + s3.z) * inv);
        atomicAdd(o + 3, (s0.w + s1.w + s2.w + s3.w) * inv);
    }
}

extern "C" void kernel_launch(void* const* d_in, const int* in_sizes, int n_in,
                              void* d_out, int out_size, void* d_ws, size_t ws_size,
                              hipStream_t stream) {
    const float* x   = (const float*)d_in[0];
    const int* spans = (const int*)d_in[1];
    float* out       = (float*)d_out;

    // d_out is re-poisoned to 0xAA before every timed launch — zero it.
    hipMemsetAsync(out, 0, (size_t)out_size * sizeof(float), stream);

    span_mean_partial<<<dim3(B_SZ, SPLITS), dim3(D_SZ), 0, stream>>>(x, spans, out);
}